// Round 1
// baseline (969.558 us; speedup 1.0000x reference)
//
#include <hip/hip_runtime.h>
#include <math.h>

#define N_NODES 50000
#define N_EDGES 800000
#define HD 128
#define BN_EPS 1e-5f

// ---- monotonic float<->uint encoding for atomicMax on float ----
__device__ __forceinline__ unsigned enc_f32(float f) {
  unsigned u = __float_as_uint(f);
  return (u & 0x80000000u) ? ~u : (u | 0x80000000u);
}
__device__ __forceinline__ float dec_f32(unsigned u) {
  unsigned b = (u & 0x80000000u) ? (u & 0x7FFFFFFFu) : ~u;
  return __uint_as_float(b);
}

// K1: per-edge score + segment max.  One wave (64 lanes) per edge, float2/lane.
__global__ __launch_bounds__(256) void edge_score(
    const float* __restrict__ ent, const float* __restrict__ rel,
    const int* __restrict__ src, const int* __restrict__ dst,
    const int* __restrict__ rid, float* __restrict__ score,
    unsigned* __restrict__ segmax) {
  int e = blockIdx.x * 4 + (threadIdx.x >> 6);
  if (e >= N_EDGES) return;
  int lane = threadIdx.x & 63;
  int s = src[e], d = dst[e], r = rid[e];
  float2 a = ((const float2*)(ent + (long)s * HD))[lane];
  float2 b = ((const float2*)(ent + (long)d * HD))[lane];
  float2 c = ((const float2*)(rel + (long)r * HD))[lane];
  float p = a.x * c.x * b.x + a.y * c.y * b.y;
#pragma unroll
  for (int off = 32; off > 0; off >>= 1) p += __shfl_xor(p, off, 64);
  if (lane == 0) {
    score[e] = p;
    atomicMax(segmax + d, enc_f32(p));
  }
}

// K2: per-edge exp + unnormalized scatter.  neigh[dst] += comp*ex, denom[dst] += ex.
__global__ __launch_bounds__(256) void edge_scatter(
    const float* __restrict__ ent, const float* __restrict__ rel,
    const int* __restrict__ src, const int* __restrict__ dst,
    const int* __restrict__ rid, const float* __restrict__ score,
    const unsigned* __restrict__ segmax,
    float* __restrict__ denom, float* __restrict__ neigh) {
  int e = blockIdx.x * 4 + (threadIdx.x >> 6);
  if (e >= N_EDGES) return;
  int lane = threadIdx.x & 63;
  int s = src[e], d = dst[e], r = rid[e];
  float ex = expf(score[e] - dec_f32(segmax[d]));
  float2 a = ((const float2*)(ent + (long)s * HD))[lane];
  float2 c = ((const float2*)(rel + (long)r * HD))[lane];
  if (lane == 0) unsafeAtomicAdd(denom + d, ex);
  float* np_ = neigh + (long)d * HD + lane * 2;
  unsafeAtomicAdd(np_ + 0, a.x * c.x * ex);
  unsafeAtomicAdd(np_ + 1, a.y * c.y * ex);
}

// K3: h = (neigh/denom) @ W.  32 rows/block, W + rows staged in LDS.
__global__ __launch_bounds__(256) void gemm_rows(
    const float* __restrict__ neigh, const float* __restrict__ denom,
    const float* __restrict__ W, float* __restrict__ h) {
  __shared__ float sW[HD * HD];   // 64 KB
  __shared__ float sN[32 * HD];   // 16 KB
  int tid = threadIdx.x;
  for (int i = tid; i < HD * HD / 4; i += 256)
    ((float4*)sW)[i] = ((const float4*)W)[i];
  int row0 = blockIdx.x * 32;
  for (int i = tid; i < 32 * HD / 4; i += 256) {
    int r = i >> 5;               // 32 float4 per row
    int gr = row0 + r;
    float4 v = make_float4(0.f, 0.f, 0.f, 0.f);
    if (gr < N_NODES) {
      v = ((const float4*)neigh)[(long)gr * 32 + (i & 31)];
      float dn = denom[gr];
      float inv = dn > 0.f ? 1.f / dn : 0.f;
      v.x *= inv; v.y *= inv; v.z *= inv; v.w *= inv;
    }
    ((float4*)sN)[i] = v;
  }
  __syncthreads();
  int r = tid >> 3;               // 0..31
  int j0 = (tid & 7) << 4;        // 0..112
  float acc[16];
#pragma unroll
  for (int jj = 0; jj < 16; ++jj) acc[jj] = 0.f;
  for (int k = 0; k < HD; ++k) {
    float a = sN[r * HD + k];
#pragma unroll
    for (int jj = 0; jj < 16; ++jj)
      acc[jj] = fmaf(a, sW[k * HD + j0 + jj], acc[jj]);
  }
  int gr = row0 + r;
  if (gr < N_NODES) {
    float4* hp = (float4*)(h + (long)gr * HD + j0);
    hp[0] = make_float4(acc[0], acc[1], acc[2], acc[3]);
    hp[1] = make_float4(acc[4], acc[5], acc[6], acc[7]);
    hp[2] = make_float4(acc[8], acc[9], acc[10], acc[11]);
    hp[3] = make_float4(acc[12], acc[13], acc[14], acc[15]);
  }
}

// K4: per-column sum / sumsq over rows of h.
__global__ __launch_bounds__(256) void col_stats(
    const float* __restrict__ h, float* __restrict__ colsum,
    float* __restrict__ colsumsq) {
  int c = threadIdx.x & 127;
  int half = threadIdx.x >> 7;
  float s = 0.f, s2 = 0.f;
  for (int r = blockIdx.x * 2 + half; r < N_NODES; r += gridDim.x * 2) {
    float v = h[(long)r * HD + c];
    s += v; s2 += v * v;
  }
  __shared__ float ls[256], ls2[256];
  ls[threadIdx.x] = s; ls2[threadIdx.x] = s2;
  __syncthreads();
  if (half == 0) {
    s = ls[c] + ls[c + 128];
    s2 = ls2[c] + ls2[c + 128];
    unsafeAtomicAdd(colsum + c, s);
    unsafeAtomicAdd(colsumsq + c, s2);
  }
}

// K5: BN (batch stats) + tanh, in place on h (= d_out).
__global__ __launch_bounds__(256) void bn_tanh(
    float* __restrict__ h, const float* __restrict__ colsum,
    const float* __restrict__ colsumsq, const float* __restrict__ gamma,
    const float* __restrict__ beta) {
  const float invN = 1.f / (float)N_NODES;
  long total = (long)N_NODES * HD;
  for (long i = (long)blockIdx.x * blockDim.x + threadIdx.x; i < total;
       i += (long)gridDim.x * blockDim.x) {
    int c = (int)(i & 127);
    float mu = colsum[c] * invN;
    float var = colsumsq[c] * invN - mu * mu;
    float v = (h[i] - mu) * rsqrtf(var + BN_EPS) * gamma[c] + beta[c];
    h[i] = tanhf(v);
  }
}

extern "C" void kernel_launch(void* const* d_in, const int* in_sizes, int n_in,
                              void* d_out, int out_size, void* d_ws, size_t ws_size,
                              hipStream_t stream) {
  const float* ent   = (const float*)d_in[0];
  const float* rel   = (const float*)d_in[1];
  const float* W     = (const float*)d_in[2];
  const float* gamma = (const float*)d_in[3];
  const float* beta  = (const float*)d_in[4];
  const int*   src   = (const int*)d_in[5];
  const int*   dst   = (const int*)d_in[6];
  const int*   rid   = (const int*)d_in[7];
  float* out = (float*)d_out;

  char* ws = (char*)d_ws;
  unsigned* segmax = (unsigned*)(ws + 0);                 // 200000 B
  float* denom     = (float*)(ws + 200000);               // 200000 B
  float* colsum    = (float*)(ws + 400000);               // 512 B
  float* colsumsq  = (float*)(ws + 400512);               // 512 B
  float* neigh     = (float*)(ws + 401024);               // 25,600,000 B
  float* score     = (float*)(ws + 26001024);             // 3,200,000 B
  // total: 29,201,024 B

  // zero segmax (0 == encoded -inf identity), denom, colsums, neigh
  hipMemsetAsync(d_ws, 0, 26001024, stream);

  dim3 eb(256);
  int eg = N_EDGES / 4;  // 4 edges per 256-thread block
  edge_score<<<eg, eb, 0, stream>>>(ent, rel, src, dst, rid, score, segmax);
  edge_scatter<<<eg, eb, 0, stream>>>(ent, rel, src, dst, rid, score, segmax,
                                      denom, neigh);
  gemm_rows<<<(N_NODES + 31) / 32, 256, 0, stream>>>(neigh, denom, W, out);
  col_stats<<<256, 256, 0, stream>>>(out, colsum, colsumsq);
  bn_tanh<<<2048, 256, 0, stream>>>(out, colsum, colsumsq, gamma, beta);
}

// Round 2
// 504.638 us; speedup vs baseline: 1.9213x; 1.9213x over previous
//
#include <hip/hip_runtime.h>
#include <math.h>

#define N_NODES 50000
#define N_EDGES 800000
#define HD 128
#define BN_EPS 1e-5f

// ---- monotonic float<->uint encoding for atomicMax on float ----
// enc of any finite/inf float is > 0, so memset-0 is the -inf identity.
__device__ __forceinline__ unsigned enc_f32(float f) {
  unsigned u = __float_as_uint(f);
  return (u & 0x80000000u) ? ~u : (u | 0x80000000u);
}
__device__ __forceinline__ float dec_f32(unsigned u) {
  unsigned b = (u & 0x80000000u) ? (u & 0x7FFFFFFFu) : ~u;
  return __uint_as_float(b);
}

// K1: per-edge score + segment max + dst histogram.  One wave per edge.
__global__ __launch_bounds__(256) void edge_score(
    const float* __restrict__ ent, const float* __restrict__ rel,
    const int* __restrict__ src, const int* __restrict__ dst,
    const int* __restrict__ rid, float* __restrict__ score,
    unsigned* __restrict__ segmax, int* __restrict__ counts) {
  int e = blockIdx.x * 4 + (threadIdx.x >> 6);
  if (e >= N_EDGES) return;
  int lane = threadIdx.x & 63;
  int s = src[e], d = dst[e], r = rid[e];
  float2 a = ((const float2*)(ent + (long)s * HD))[lane];
  float2 b = ((const float2*)(ent + (long)d * HD))[lane];
  float2 c = ((const float2*)(rel + (long)r * HD))[lane];
  float p = a.x * c.x * b.x + a.y * c.y * b.y;
#pragma unroll
  for (int off = 32; off > 0; off >>= 1) p += __shfl_xor(p, off, 64);
  if (lane == 0) {
    score[e] = p;
    atomicMax(segmax + d, enc_f32(p));
    atomicAdd(counts + d, 1);
  }
}

// K2: exclusive scan of counts[50000] -> offsets[50001].  Single block.
__global__ __launch_bounds__(256) void scan_counts(
    const int* __restrict__ counts, int* __restrict__ offsets) {
  __shared__ int ls[256];
  const int CH = (N_NODES + 255) / 256;  // 196
  int t = threadIdx.x;
  int base = t * CH;
  int s = 0;
  for (int i = 0; i < CH; ++i) {
    int idx = base + i;
    if (idx < N_NODES) s += counts[idx];
  }
  ls[t] = s;
  __syncthreads();
  // Hillis-Steele inclusive scan in LDS
  for (int off = 1; off < 256; off <<= 1) {
    int u = (t >= off) ? ls[t - off] : 0;
    __syncthreads();
    ls[t] += u;
    __syncthreads();
  }
  int run = ls[t] - s;  // exclusive prefix of this chunk
  for (int i = 0; i < CH; ++i) {
    int idx = base + i;
    if (idx < N_NODES) {
      offsets[idx] = run;
      run += counts[idx];
    }
  }
  if (t == 255) offsets[N_NODES] = run;
}

// K3: bucket edges by dst, packing {src, rid, score} into 16B records.
__global__ __launch_bounds__(256) void fill_buckets(
    const int* __restrict__ src, const int* __restrict__ dst,
    const int* __restrict__ rid, const float* __restrict__ score,
    const int* __restrict__ offsets, int* __restrict__ cursor,
    int4* __restrict__ einfo) {
  int e = blockIdx.x * 256 + threadIdx.x;
  if (e >= N_EDGES) return;
  int d = dst[e];
  int pos = atomicAdd(cursor + d, 1);
  int4 v;
  v.x = src[e];
  v.y = rid[e];
  v.z = __float_as_int(score[e]);
  v.w = 0;
  einfo[offsets[d] + pos] = v;
}

// K4: gather per dst node.  One wave per node; accumulate comp*ex and sum ex
// in registers; single 512B row write of the normalized result.
__global__ __launch_bounds__(256) void gather(
    const float* __restrict__ ent, const float* __restrict__ rel,
    const int* __restrict__ offsets, const int4* __restrict__ einfo,
    const unsigned* __restrict__ segmax, float* __restrict__ scaled) {
  int n = blockIdx.x * 4 + (threadIdx.x >> 6);
  if (n >= N_NODES) return;
  int lane = threadIdx.x & 63;
  int s0 = __builtin_amdgcn_readfirstlane(offsets[n]);
  int s1 = __builtin_amdgcn_readfirstlane(offsets[n + 1]);
  float m = dec_f32(segmax[n]);
  float den = 0.f, ax = 0.f, ay = 0.f;
  for (int s = s0; s < s1; ++s) {
    int4 v = einfo[s];  // wave-uniform address
    float ex = __expf(__int_as_float(v.z) - m);
    float2 a = ((const float2*)(ent + (long)v.x * HD))[lane];
    float2 c = ((const float2*)(rel + (long)v.y * HD))[lane];
    den += ex;
    ax = fmaf(a.x * c.x, ex, ax);
    ay = fmaf(a.y * c.y, ex, ay);
  }
  float inv = den > 0.f ? 1.f / den : 0.f;
  ((float2*)(scaled + (long)n * HD))[lane] = make_float2(ax * inv, ay * inv);
}

// K5: h = scaled @ W.  32 rows/block, W + rows staged in LDS.
__global__ __launch_bounds__(256) void gemm_rows(
    const float* __restrict__ scaled, const float* __restrict__ W,
    float* __restrict__ h) {
  __shared__ float sW[HD * HD];  // 64 KB
  __shared__ float sN[32 * HD];  // 16 KB
  int tid = threadIdx.x;
  for (int i = tid; i < HD * HD / 4; i += 256)
    ((float4*)sW)[i] = ((const float4*)W)[i];
  int row0 = blockIdx.x * 32;
  for (int i = tid; i < 32 * HD / 4; i += 256) {
    int r = i >> 5;
    int gr = row0 + r;
    float4 v = make_float4(0.f, 0.f, 0.f, 0.f);
    if (gr < N_NODES) v = ((const float4*)scaled)[(long)gr * 32 + (i & 31)];
    ((float4*)sN)[i] = v;
  }
  __syncthreads();
  int r = tid >> 3;         // 0..31
  int j0 = (tid & 7) << 4;  // 0..112
  float acc[16];
#pragma unroll
  for (int jj = 0; jj < 16; ++jj) acc[jj] = 0.f;
  for (int k = 0; k < HD; ++k) {
    float a = sN[r * HD + k];
    const float4* wrow = (const float4*)(sW + k * HD + j0);
#pragma unroll
    for (int q = 0; q < 4; ++q) {
      float4 w = wrow[q];
      acc[q * 4 + 0] = fmaf(a, w.x, acc[q * 4 + 0]);
      acc[q * 4 + 1] = fmaf(a, w.y, acc[q * 4 + 1]);
      acc[q * 4 + 2] = fmaf(a, w.z, acc[q * 4 + 2]);
      acc[q * 4 + 3] = fmaf(a, w.w, acc[q * 4 + 3]);
    }
  }
  int gr = row0 + r;
  if (gr < N_NODES) {
    float4* hp = (float4*)(h + (long)gr * HD + j0);
    hp[0] = make_float4(acc[0], acc[1], acc[2], acc[3]);
    hp[1] = make_float4(acc[4], acc[5], acc[6], acc[7]);
    hp[2] = make_float4(acc[8], acc[9], acc[10], acc[11]);
    hp[3] = make_float4(acc[12], acc[13], acc[14], acc[15]);
  }
}

// K6: per-column sum / sumsq over rows of h.
__global__ __launch_bounds__(256) void col_stats(
    const float* __restrict__ h, float* __restrict__ colsum,
    float* __restrict__ colsumsq) {
  int c = threadIdx.x & 127;
  int half = threadIdx.x >> 7;
  float s = 0.f, s2 = 0.f;
  for (int r = blockIdx.x * 2 + half; r < N_NODES; r += gridDim.x * 2) {
    float v = h[(long)r * HD + c];
    s += v;
    s2 += v * v;
  }
  __shared__ float ls[256], ls2[256];
  ls[threadIdx.x] = s;
  ls2[threadIdx.x] = s2;
  __syncthreads();
  if (half == 0) {
    s = ls[c] + ls[c + 128];
    s2 = ls2[c] + ls2[c + 128];
    unsafeAtomicAdd(colsum + c, s);
    unsafeAtomicAdd(colsumsq + c, s2);
  }
}

// K7: BN (batch stats) + tanh, h (ws) -> out.
__global__ __launch_bounds__(256) void bn_tanh(
    const float* __restrict__ h, const float* __restrict__ colsum,
    const float* __restrict__ colsumsq, const float* __restrict__ gamma,
    const float* __restrict__ beta, float* __restrict__ out) {
  const float invN = 1.f / (float)N_NODES;
  long total = (long)N_NODES * HD;
  for (long i = (long)blockIdx.x * blockDim.x + threadIdx.x; i < total;
       i += (long)gridDim.x * blockDim.x) {
    int c = (int)(i & 127);
    float mu = colsum[c] * invN;
    float var = colsumsq[c] * invN - mu * mu;
    float v = (h[i] - mu) * rsqrtf(var + BN_EPS) * gamma[c] + beta[c];
    out[i] = tanhf(v);
  }
}

extern "C" void kernel_launch(void* const* d_in, const int* in_sizes, int n_in,
                              void* d_out, int out_size, void* d_ws, size_t ws_size,
                              hipStream_t stream) {
  const float* ent   = (const float*)d_in[0];
  const float* rel   = (const float*)d_in[1];
  const float* W     = (const float*)d_in[2];
  const float* gamma = (const float*)d_in[3];
  const float* beta  = (const float*)d_in[4];
  const int*   src   = (const int*)d_in[5];
  const int*   dst   = (const int*)d_in[6];
  const int*   rid   = (const int*)d_in[7];
  float* out = (float*)d_out;

  char* ws = (char*)d_ws;
  unsigned* segmax = (unsigned*)(ws + 0);        // 200,000 B
  int* counts      = (int*)(ws + 200000);        // 200,000 B
  int* cursor      = (int*)(ws + 400000);        // 200,000 B
  float* colsum    = (float*)(ws + 600000);      // 512 B
  float* colsumsq  = (float*)(ws + 600512);      // 512 B
  int* offsets     = (int*)(ws + 601024);        // 200,004 B -> 801,028
  // region reused over time:
  int4* einfo      = (int4*)(ws + 801040);       // 12,800,000 B -> 13,601,040
  float* score     = (float*)(ws + 13601040);    // 3,200,000 B  -> 16,801,040
  float* h         = (float*)(ws + 801040);      // 25,600,000 B (overlaps einfo+score,
                                                 //  written only after both are dead)
  float* scaled    = out;                        // gather result lives in d_out
  // ws bytes used: 26,401,040

  // zero: segmax (enc(-inf) identity), counts, cursor, colsum/colsumsq
  hipMemsetAsync(d_ws, 0, 601024, stream);

  int eg = N_EDGES / 4;  // 4 edges per 256-thread block (wave per edge)
  edge_score<<<eg, 256, 0, stream>>>(ent, rel, src, dst, rid, score, segmax, counts);
  scan_counts<<<1, 256, 0, stream>>>(counts, offsets);
  fill_buckets<<<(N_EDGES + 255) / 256, 256, 0, stream>>>(src, dst, rid, score,
                                                          offsets, cursor, einfo);
  gather<<<(N_NODES + 3) / 4, 256, 0, stream>>>(ent, rel, offsets, einfo, segmax,
                                                scaled);
  gemm_rows<<<(N_NODES + 31) / 32, 256, 0, stream>>>(scaled, W, out /*unused*/ == out ? (float*)h : (float*)h);
  // (gemm reads `scaled` == d_out, writes h in ws)
  col_stats<<<256, 256, 0, stream>>>(h, colsum, colsumsq);
  bn_tanh<<<2048, 256, 0, stream>>>(h, colsum, colsumsq, gamma, beta, out);
}

// Round 3
// 385.545 us; speedup vs baseline: 2.5148x; 1.3089x over previous
//
#include <hip/hip_runtime.h>
#include <math.h>

#define N_NODES 50000
#define N_EDGES 800000
#define HD 128
#define BN_EPS 1e-5f

// K1: dst-degree histogram.  4 edges/thread via int4.
__global__ __launch_bounds__(256) void hist(const int* __restrict__ dst,
                                            int* __restrict__ counts) {
  int i = blockIdx.x * 256 + threadIdx.x;
  if (i >= N_EDGES / 4) return;
  int4 d = ((const int4*)dst)[i];
  atomicAdd(counts + d.x, 1);
  atomicAdd(counts + d.y, 1);
  atomicAdd(counts + d.z, 1);
  atomicAdd(counts + d.w, 1);
}

// K2: exclusive scan of counts[N_NODES] -> offsets[N_NODES+1].  Single block.
__global__ __launch_bounds__(256) void scan_counts(
    const int* __restrict__ counts, int* __restrict__ offsets) {
  __shared__ int ls[256];
  const int CH = (N_NODES + 255) / 256;  // 196
  int t = threadIdx.x;
  int base = t * CH;
  int s = 0;
  for (int i = 0; i < CH; ++i) {
    int idx = base + i;
    if (idx < N_NODES) s += counts[idx];
  }
  ls[t] = s;
  __syncthreads();
  for (int off = 1; off < 256; off <<= 1) {
    int u = (t >= off) ? ls[t - off] : 0;
    __syncthreads();
    ls[t] += u;
    __syncthreads();
  }
  int run = ls[t] - s;
  for (int i = 0; i < CH; ++i) {
    int idx = base + i;
    if (idx < N_NODES) {
      offsets[idx] = run;
      run += counts[idx];
    }
  }
  if (t == 255) offsets[N_NODES] = run;
}

// K3: bucket edges by dst, packing {src, rid} into 8B records.
__global__ __launch_bounds__(256) void fill_buckets(
    const int* __restrict__ src, const int* __restrict__ dst,
    const int* __restrict__ rid, const int* __restrict__ offsets,
    int* __restrict__ cursor, int2* __restrict__ einfo) {
  int i = blockIdx.x * 256 + threadIdx.x;
  if (i >= N_EDGES / 4) return;
  int4 s4 = ((const int4*)src)[i];
  int4 d4 = ((const int4*)dst)[i];
  int4 r4 = ((const int4*)rid)[i];
#pragma unroll
  for (int q = 0; q < 4; ++q) {
    int s = (q == 0) ? s4.x : (q == 1) ? s4.y : (q == 2) ? s4.z : s4.w;
    int d = (q == 0) ? d4.x : (q == 1) ? d4.y : (q == 2) ? d4.z : d4.w;
    int r = (q == 0) ? r4.x : (q == 1) ? r4.y : (q == 2) ? r4.z : r4.w;
    int pos = atomicAdd(cursor + d, 1);
    einfo[offsets[d] + pos] = make_int2(s, r);
  }
}

// K4: fused score + online-softmax + aggregation.  One wave per dst node.
// Per edge: comp = ent[src]*rel[rid]; p = dot(comp, ent[dst]); online update.
__global__ __launch_bounds__(256) void gather_fused(
    const float* __restrict__ ent, const float* __restrict__ rel,
    const int* __restrict__ offsets, const int2* __restrict__ einfo,
    float* __restrict__ scaled) {
  int n = blockIdx.x * 4 + (threadIdx.x >> 6);
  if (n >= N_NODES) return;
  int lane = threadIdx.x & 63;
  int s0 = __builtin_amdgcn_readfirstlane(offsets[n]);
  int s1 = __builtin_amdgcn_readfirstlane(offsets[n + 1]);
  float2 b = ((const float2*)(ent + (long)n * HD))[lane];
  float m = -INFINITY, den = 0.f, ax = 0.f, ay = 0.f;
  for (int s = s0; s < s1; ++s) {
    int2 v = einfo[s];  // wave-uniform
    float2 a = ((const float2*)(ent + (long)v.x * HD))[lane];
    float2 c = ((const float2*)(rel + (long)v.y * HD))[lane];
    float cx = a.x * c.x, cy = a.y * c.y;
    float p = cx * b.x + cy * b.y;
#pragma unroll
    for (int off = 32; off > 0; off >>= 1) p += __shfl_xor(p, off, 64);
    float mn = fmaxf(m, p);
    float f = __expf(m - mn);  // first edge: exp(-inf) = 0
    float e = __expf(p - mn);
    den = den * f + e;
    ax = ax * f + cx * e;
    ay = ay * f + cy * e;
    m = mn;
  }
  float inv = den > 0.f ? 1.f / den : 0.f;
  ((float2*)(scaled + (long)n * HD))[lane] = make_float2(ax * inv, ay * inv);
}

// K5: h = scaled @ W.  32 rows/block, W + rows staged in LDS.
__global__ __launch_bounds__(256) void gemm_rows(
    const float* __restrict__ scaled, const float* __restrict__ W,
    float* __restrict__ h) {
  __shared__ float sW[HD * HD];  // 64 KB
  __shared__ float sN[32 * HD];  // 16 KB
  int tid = threadIdx.x;
  for (int i = tid; i < HD * HD / 4; i += 256)
    ((float4*)sW)[i] = ((const float4*)W)[i];
  int row0 = blockIdx.x * 32;
  for (int i = tid; i < 32 * HD / 4; i += 256) {
    int r = i >> 5;
    int gr = row0 + r;
    float4 v = make_float4(0.f, 0.f, 0.f, 0.f);
    if (gr < N_NODES) v = ((const float4*)scaled)[(long)gr * 32 + (i & 31)];
    ((float4*)sN)[i] = v;
  }
  __syncthreads();
  int r = tid >> 3;         // 0..31
  int j0 = (tid & 7) << 4;  // 0..112
  float acc[16];
#pragma unroll
  for (int jj = 0; jj < 16; ++jj) acc[jj] = 0.f;
  for (int k = 0; k < HD; ++k) {
    float a = sN[r * HD + k];
    const float4* wrow = (const float4*)(sW + k * HD + j0);
#pragma unroll
    for (int q = 0; q < 4; ++q) {
      float4 w = wrow[q];
      acc[q * 4 + 0] = fmaf(a, w.x, acc[q * 4 + 0]);
      acc[q * 4 + 1] = fmaf(a, w.y, acc[q * 4 + 1]);
      acc[q * 4 + 2] = fmaf(a, w.z, acc[q * 4 + 2]);
      acc[q * 4 + 3] = fmaf(a, w.w, acc[q * 4 + 3]);
    }
  }
  int gr = row0 + r;
  if (gr < N_NODES) {
    float4* hp = (float4*)(h + (long)gr * HD + j0);
    hp[0] = make_float4(acc[0], acc[1], acc[2], acc[3]);
    hp[1] = make_float4(acc[4], acc[5], acc[6], acc[7]);
    hp[2] = make_float4(acc[8], acc[9], acc[10], acc[11]);
    hp[3] = make_float4(acc[12], acc[13], acc[14], acc[15]);
  }
}

// K6: per-column sum / sumsq over rows of h.
__global__ __launch_bounds__(256) void col_stats(
    const float* __restrict__ h, float* __restrict__ colsum,
    float* __restrict__ colsumsq) {
  int c = threadIdx.x & 127;
  int half = threadIdx.x >> 7;
  float s = 0.f, s2 = 0.f;
  for (int r = blockIdx.x * 2 + half; r < N_NODES; r += gridDim.x * 2) {
    float v = h[(long)r * HD + c];
    s += v;
    s2 += v * v;
  }
  __shared__ float ls[256], ls2[256];
  ls[threadIdx.x] = s;
  ls2[threadIdx.x] = s2;
  __syncthreads();
  if (half == 0) {
    s = ls[c] + ls[c + 128];
    s2 = ls2[c] + ls2[c + 128];
    unsafeAtomicAdd(colsum + c, s);
    unsafeAtomicAdd(colsumsq + c, s2);
  }
}

// K7: BN (batch stats) + tanh, h (ws) -> out.
__global__ __launch_bounds__(256) void bn_tanh(
    const float* __restrict__ h, const float* __restrict__ colsum,
    const float* __restrict__ colsumsq, const float* __restrict__ gamma,
    const float* __restrict__ beta, float* __restrict__ out) {
  const float invN = 1.f / (float)N_NODES;
  long total = (long)N_NODES * HD;
  for (long i = (long)blockIdx.x * blockDim.x + threadIdx.x; i < total;
       i += (long)gridDim.x * blockDim.x) {
    int c = (int)(i & 127);
    float mu = colsum[c] * invN;
    float var = colsumsq[c] * invN - mu * mu;
    float v = (h[i] - mu) * rsqrtf(var + BN_EPS) * gamma[c] + beta[c];
    out[i] = tanhf(v);
  }
}

extern "C" void kernel_launch(void* const* d_in, const int* in_sizes, int n_in,
                              void* d_out, int out_size, void* d_ws, size_t ws_size,
                              hipStream_t stream) {
  const float* ent   = (const float*)d_in[0];
  const float* rel   = (const float*)d_in[1];
  const float* W     = (const float*)d_in[2];
  const float* gamma = (const float*)d_in[3];
  const float* beta  = (const float*)d_in[4];
  const int*   src   = (const int*)d_in[5];
  const int*   dst   = (const int*)d_in[6];
  const int*   rid   = (const int*)d_in[7];
  float* out = (float*)d_out;

  char* ws = (char*)d_ws;
  int* counts      = (int*)(ws + 0);           // 200,000 B
  int* cursor      = (int*)(ws + 200000);      // 200,000 B
  float* colsum    = (float*)(ws + 400000);    // 512 B
  float* colsumsq  = (float*)(ws + 400512);    // 512 B   (zeroed region ends 401,024)
  int* offsets     = (int*)(ws + 401024);      // 200,004 B -> 601,028
  // einfo (6.4 MB) and h (25.6 MB) share the same region: einfo is dead
  // before gemm_rows writes h (strict stream ordering).
  int2* einfo      = (int2*)(ws + 601088);     // 6,400,000 B
  float* h         = (float*)(ws + 601088);    // 25,600,000 B -> 26,201,088 total
  float* scaled    = out;                      // gather result lives in d_out

  // zero: counts, cursor, colsum, colsumsq
  hipMemsetAsync(d_ws, 0, 401024, stream);

  hist<<<(N_EDGES / 4 + 255) / 256, 256, 0, stream>>>(dst, counts);
  scan_counts<<<1, 256, 0, stream>>>(counts, offsets);
  fill_buckets<<<(N_EDGES / 4 + 255) / 256, 256, 0, stream>>>(src, dst, rid,
                                                              offsets, cursor, einfo);
  gather_fused<<<(N_NODES + 3) / 4, 256, 0, stream>>>(ent, rel, offsets, einfo,
                                                      scaled);
  gemm_rows<<<(N_NODES + 31) / 32, 256, 0, stream>>>(scaled, W, h);
  col_stats<<<256, 256, 0, stream>>>(h, colsum, colsumsq);
  bn_tanh<<<2048, 256, 0, stream>>>(h, colsum, colsumsq, gamma, beta, out);
}

// Round 4
// 267.595 us; speedup vs baseline: 3.6232x; 1.4408x over previous
//
#include <hip/hip_runtime.h>
#include <math.h>

#define N_NODES 50000
#define N_EDGES 800000
#define HD 128
#define BN_EPS 1e-5f

#define SCAN_CHUNK 1024                       // elements per scan block
#define SCAN_NB ((N_NODES + SCAN_CHUNK - 1) / SCAN_CHUNK)  // 49

// K1: dst-degree histogram.  4 edges/thread via int4.
__global__ __launch_bounds__(256) void hist(const int* __restrict__ dst,
                                            int* __restrict__ counts) {
  int i = blockIdx.x * 256 + threadIdx.x;
  if (i >= N_EDGES / 4) return;
  int4 d = ((const int4*)dst)[i];
  atomicAdd(counts + d.x, 1);
  atomicAdd(counts + d.y, 1);
  atomicAdd(counts + d.z, 1);
  atomicAdd(counts + d.w, 1);
}

// K2a: per-block partial sums of counts (1024 elements / block).
__global__ __launch_bounds__(256) void scan_blocks(
    const int* __restrict__ counts, int* __restrict__ bsum) {
  int t = threadIdx.x;
  int idx = blockIdx.x * SCAN_CHUNK + t * 4;
  int s = 0;
  if (idx + 3 < N_NODES) {
    int4 v = *(const int4*)(counts + idx);
    s = v.x + v.y + v.z + v.w;
  } else {
#pragma unroll
    for (int j = 0; j < 4; ++j)
      if (idx + j < N_NODES) s += counts[idx + j];
  }
  __shared__ int ls[256];
  ls[t] = s;
  __syncthreads();
  for (int off = 128; off > 0; off >>= 1) {
    if (t < off) ls[t] += ls[t + off];
    __syncthreads();
  }
  if (t == 0) bsum[blockIdx.x] = ls[0];
}

// K2b: one wave scans the SCAN_NB partials -> exclusive bases + grand total.
__global__ __launch_bounds__(64) void scan_top(const int* __restrict__ bsum,
                                               int* __restrict__ bbase,
                                               int* __restrict__ offsets) {
  int t = threadIdx.x;
  int v = (t < SCAN_NB) ? bsum[t] : 0;
  int incl = v;
#pragma unroll
  for (int off = 1; off < 64; off <<= 1) {
    int u = __shfl_up(incl, off, 64);
    if (t >= off) incl += u;
  }
  if (t < SCAN_NB) bbase[t] = incl - v;
  if (t == 63) offsets[N_NODES] = incl;  // grand total
}

// K2c: per-block exclusive scan + base -> offsets.
__global__ __launch_bounds__(256) void scan_write(
    const int* __restrict__ counts, const int* __restrict__ bbase,
    int* __restrict__ offsets) {
  int t = threadIdx.x;
  int idx = blockIdx.x * SCAN_CHUNK + t * 4;
  int c[4] = {0, 0, 0, 0};
  if (idx + 3 < N_NODES) {
    int4 v = *(const int4*)(counts + idx);
    c[0] = v.x; c[1] = v.y; c[2] = v.z; c[3] = v.w;
  } else {
#pragma unroll
    for (int j = 0; j < 4; ++j)
      if (idx + j < N_NODES) c[j] = counts[idx + j];
  }
  int s = c[0] + c[1] + c[2] + c[3];
  __shared__ int ls[256];
  ls[t] = s;
  __syncthreads();
  // Hillis-Steele inclusive scan over 256 thread sums
  for (int off = 1; off < 256; off <<= 1) {
    int u = (t >= off) ? ls[t - off] : 0;
    __syncthreads();
    ls[t] += u;
    __syncthreads();
  }
  int run = bbase[blockIdx.x] + ls[t] - s;  // exclusive prefix for this thread
#pragma unroll
  for (int j = 0; j < 4; ++j) {
    if (idx + j < N_NODES) {
      offsets[idx + j] = run;
      run += c[j];
    }
  }
}

// K3: bucket edges by dst, packing {src, rid} into 8B records.
__global__ __launch_bounds__(256) void fill_buckets(
    const int* __restrict__ src, const int* __restrict__ dst,
    const int* __restrict__ rid, const int* __restrict__ offsets,
    int* __restrict__ cursor, int2* __restrict__ einfo) {
  int i = blockIdx.x * 256 + threadIdx.x;
  if (i >= N_EDGES / 4) return;
  int4 s4 = ((const int4*)src)[i];
  int4 d4 = ((const int4*)dst)[i];
  int4 r4 = ((const int4*)rid)[i];
#pragma unroll
  for (int q = 0; q < 4; ++q) {
    int s = (q == 0) ? s4.x : (q == 1) ? s4.y : (q == 2) ? s4.z : s4.w;
    int d = (q == 0) ? d4.x : (q == 1) ? d4.y : (q == 2) ? d4.z : d4.w;
    int r = (q == 0) ? r4.x : (q == 1) ? r4.y : (q == 2) ? r4.z : r4.w;
    int pos = atomicAdd(cursor + d, 1);
    einfo[offsets[d] + pos] = make_int2(s, r);
  }
}

// K4: fused score + online-softmax + aggregation.  One wave per dst node,
// edge loop unrolled x4 (independent gathers + pipelined shuffle reduces,
// one batched online-softmax rescale per 4 edges).
__global__ __launch_bounds__(256) void gather_fused(
    const float* __restrict__ ent, const float* __restrict__ rel,
    const int* __restrict__ offsets, const int2* __restrict__ einfo,
    float* __restrict__ scaled) {
  int n = blockIdx.x * 4 + (threadIdx.x >> 6);
  if (n >= N_NODES) return;
  int lane = threadIdx.x & 63;
  int s0 = __builtin_amdgcn_readfirstlane(offsets[n]);
  int s1 = __builtin_amdgcn_readfirstlane(offsets[n + 1]);
  float2 b = ((const float2*)(ent + (long)n * HD))[lane];
  float m = -INFINITY, den = 0.f, ax = 0.f, ay = 0.f;
  int s = s0;
  for (; s + 4 <= s1; s += 4) {
    int2 v0 = einfo[s + 0];
    int2 v1 = einfo[s + 1];
    int2 v2 = einfo[s + 2];
    int2 v3 = einfo[s + 3];
    float2 a0 = ((const float2*)(ent + (long)v0.x * HD))[lane];
    float2 c0 = ((const float2*)(rel + (long)v0.y * HD))[lane];
    float2 a1 = ((const float2*)(ent + (long)v1.x * HD))[lane];
    float2 c1 = ((const float2*)(rel + (long)v1.y * HD))[lane];
    float2 a2 = ((const float2*)(ent + (long)v2.x * HD))[lane];
    float2 c2 = ((const float2*)(rel + (long)v2.y * HD))[lane];
    float2 a3 = ((const float2*)(ent + (long)v3.x * HD))[lane];
    float2 c3 = ((const float2*)(rel + (long)v3.y * HD))[lane];
    float cx0 = a0.x * c0.x, cy0 = a0.y * c0.y;
    float cx1 = a1.x * c1.x, cy1 = a1.y * c1.y;
    float cx2 = a2.x * c2.x, cy2 = a2.y * c2.y;
    float cx3 = a3.x * c3.x, cy3 = a3.y * c3.y;
    float p0 = cx0 * b.x + cy0 * b.y;
    float p1 = cx1 * b.x + cy1 * b.y;
    float p2 = cx2 * b.x + cy2 * b.y;
    float p3 = cx3 * b.x + cy3 * b.y;
#pragma unroll
    for (int off = 32; off > 0; off >>= 1) {
      p0 += __shfl_xor(p0, off, 64);
      p1 += __shfl_xor(p1, off, 64);
      p2 += __shfl_xor(p2, off, 64);
      p3 += __shfl_xor(p3, off, 64);
    }
    float pm = fmaxf(fmaxf(fmaxf(p0, p1), fmaxf(p2, p3)), m);
    float f = __expf(m - pm);
    float e0 = __expf(p0 - pm);
    float e1 = __expf(p1 - pm);
    float e2 = __expf(p2 - pm);
    float e3 = __expf(p3 - pm);
    den = den * f + ((e0 + e1) + (e2 + e3));
    ax = ax * f + cx0 * e0 + cx1 * e1 + cx2 * e2 + cx3 * e3;
    ay = ay * f + cy0 * e0 + cy1 * e1 + cy2 * e2 + cy3 * e3;
    m = pm;
  }
  for (; s < s1; ++s) {
    int2 v = einfo[s];
    float2 a = ((const float2*)(ent + (long)v.x * HD))[lane];
    float2 c = ((const float2*)(rel + (long)v.y * HD))[lane];
    float cx = a.x * c.x, cy = a.y * c.y;
    float p = cx * b.x + cy * b.y;
#pragma unroll
    for (int off = 32; off > 0; off >>= 1) p += __shfl_xor(p, off, 64);
    float mn = fmaxf(m, p);
    float f = __expf(m - mn);
    float e = __expf(p - mn);
    den = den * f + e;
    ax = ax * f + cx * e;
    ay = ay * f + cy * e;
    m = mn;
  }
  float inv = den > 0.f ? 1.f / den : 0.f;
  ((float2*)(scaled + (long)n * HD))[lane] = make_float2(ax * inv, ay * inv);
}

// K5: h = scaled @ W.  32 rows/block, W + rows staged in LDS.
__global__ __launch_bounds__(256) void gemm_rows(
    const float* __restrict__ scaled, const float* __restrict__ W,
    float* __restrict__ h) {
  __shared__ float sW[HD * HD];  // 64 KB
  __shared__ float sN[32 * HD];  // 16 KB
  int tid = threadIdx.x;
  for (int i = tid; i < HD * HD / 4; i += 256)
    ((float4*)sW)[i] = ((const float4*)W)[i];
  int row0 = blockIdx.x * 32;
  for (int i = tid; i < 32 * HD / 4; i += 256) {
    int r = i >> 5;
    int gr = row0 + r;
    float4 v = make_float4(0.f, 0.f, 0.f, 0.f);
    if (gr < N_NODES) v = ((const float4*)scaled)[(long)gr * 32 + (i & 31)];
    ((float4*)sN)[i] = v;
  }
  __syncthreads();
  int r = tid >> 3;         // 0..31
  int j0 = (tid & 7) << 4;  // 0..112
  float acc[16];
#pragma unroll
  for (int jj = 0; jj < 16; ++jj) acc[jj] = 0.f;
  for (int k = 0; k < HD; ++k) {
    float a = sN[r * HD + k];
    const float4* wrow = (const float4*)(sW + k * HD + j0);
#pragma unroll
    for (int q = 0; q < 4; ++q) {
      float4 w = wrow[q];
      acc[q * 4 + 0] = fmaf(a, w.x, acc[q * 4 + 0]);
      acc[q * 4 + 1] = fmaf(a, w.y, acc[q * 4 + 1]);
      acc[q * 4 + 2] = fmaf(a, w.z, acc[q * 4 + 2]);
      acc[q * 4 + 3] = fmaf(a, w.w, acc[q * 4 + 3]);
    }
  }
  int gr = row0 + r;
  if (gr < N_NODES) {
    float4* hp = (float4*)(h + (long)gr * HD + j0);
    hp[0] = make_float4(acc[0], acc[1], acc[2], acc[3]);
    hp[1] = make_float4(acc[4], acc[5], acc[6], acc[7]);
    hp[2] = make_float4(acc[8], acc[9], acc[10], acc[11]);
    hp[3] = make_float4(acc[12], acc[13], acc[14], acc[15]);
  }
}

// K6: per-column sum / sumsq over rows of h.
__global__ __launch_bounds__(256) void col_stats(
    const float* __restrict__ h, float* __restrict__ colsum,
    float* __restrict__ colsumsq) {
  int c = threadIdx.x & 127;
  int half = threadIdx.x >> 7;
  float s = 0.f, s2 = 0.f;
  for (int r = blockIdx.x * 2 + half; r < N_NODES; r += gridDim.x * 2) {
    float v = h[(long)r * HD + c];
    s += v;
    s2 += v * v;
  }
  __shared__ float ls[256], ls2[256];
  ls[threadIdx.x] = s;
  ls2[threadIdx.x] = s2;
  __syncthreads();
  if (half == 0) {
    s = ls[c] + ls[c + 128];
    s2 = ls2[c] + ls2[c + 128];
    unsafeAtomicAdd(colsum + c, s);
    unsafeAtomicAdd(colsumsq + c, s2);
  }
}

// K7: BN (batch stats) + tanh, h (ws) -> out.
__global__ __launch_bounds__(256) void bn_tanh(
    const float* __restrict__ h, const float* __restrict__ colsum,
    const float* __restrict__ colsumsq, const float* __restrict__ gamma,
    const float* __restrict__ beta, float* __restrict__ out) {
  const float invN = 1.f / (float)N_NODES;
  long total = (long)N_NODES * HD;
  for (long i = (long)blockIdx.x * blockDim.x + threadIdx.x; i < total;
       i += (long)gridDim.x * blockDim.x) {
    int c = (int)(i & 127);
    float mu = colsum[c] * invN;
    float var = colsumsq[c] * invN - mu * mu;
    float v = (h[i] - mu) * rsqrtf(var + BN_EPS) * gamma[c] + beta[c];
    out[i] = tanhf(v);
  }
}

extern "C" void kernel_launch(void* const* d_in, const int* in_sizes, int n_in,
                              void* d_out, int out_size, void* d_ws, size_t ws_size,
                              hipStream_t stream) {
  const float* ent   = (const float*)d_in[0];
  const float* rel   = (const float*)d_in[1];
  const float* W     = (const float*)d_in[2];
  const float* gamma = (const float*)d_in[3];
  const float* beta  = (const float*)d_in[4];
  const int*   src   = (const int*)d_in[5];
  const int*   dst   = (const int*)d_in[6];
  const int*   rid   = (const int*)d_in[7];
  float* out = (float*)d_out;

  char* ws = (char*)d_ws;
  int* counts      = (int*)(ws + 0);           // 200,000 B
  int* cursor      = (int*)(ws + 200000);      // 200,000 B
  float* colsum    = (float*)(ws + 400000);    // 512 B
  float* colsumsq  = (float*)(ws + 400512);    // 512 B   (zeroed region ends 401,024)
  int* bsum        = (int*)(ws + 401024);      // 1,024 B (SCAN_NB=49 used)
  int* bbase       = (int*)(ws + 402048);      // 1,024 B
  int* offsets     = (int*)(ws + 403072);      // 200,004 B -> 603,076
  // einfo (6.4 MB) and h (25.6 MB) share the same region: einfo is dead
  // before gemm_rows writes h (strict stream ordering).
  int2* einfo      = (int2*)(ws + 603136);     // 6,400,000 B
  float* h         = (float*)(ws + 603136);    // 25,600,000 B -> 26,203,136 total
  float* scaled    = out;                      // gather result lives in d_out

  // zero: counts, cursor, colsum, colsumsq
  hipMemsetAsync(d_ws, 0, 401024, stream);

  hist<<<(N_EDGES / 4 + 255) / 256, 256, 0, stream>>>(dst, counts);
  scan_blocks<<<SCAN_NB, 256, 0, stream>>>(counts, bsum);
  scan_top<<<1, 64, 0, stream>>>(bsum, bbase, offsets);
  scan_write<<<SCAN_NB, 256, 0, stream>>>(counts, bbase, offsets);
  fill_buckets<<<(N_EDGES / 4 + 255) / 256, 256, 0, stream>>>(src, dst, rid,
                                                              offsets, cursor, einfo);
  gather_fused<<<(N_NODES + 3) / 4, 256, 0, stream>>>(ent, rel, offsets, einfo,
                                                      scaled);
  gemm_rows<<<(N_NODES + 31) / 32, 256, 0, stream>>>(scaled, W, h);
  col_stats<<<256, 256, 0, stream>>>(h, colsum, colsumsq);
  bn_tanh<<<2048, 256, 0, stream>>>(h, colsum, colsumsq, gamma, beta, out);
}